// Round 1
// baseline (41.087 us; speedup 1.0000x reference)
//
#include <hip/hip_runtime.h>
#include <math.h>

// Attn energies + softmax, MI355X.
// energies = E @ (W^T h)  (b*h constant cancels in softmax)
// H=1024, S=32768, all fp32.

#define H 1024
#define S 32768

// ---------------- K1: partial_v[ic][k] = sum_{j in 64-row chunk ic} W[j][k]*h[j]
// grid 64 = 16 i-chunks x 4 j-tiles, block 256. Coalesced 1KB row segments.
__global__ __launch_bounds__(256) void k1_v_partial(const float* __restrict__ W,
                                                    const float* __restrict__ h,
                                                    float* __restrict__ partial_v) {
    int ic = blockIdx.x >> 2;        // 16 chunks of 64 rows
    int jt = blockIdx.x & 3;         // 4 col tiles of 256
    int k  = jt * 256 + threadIdx.x; // column this thread owns
    int j0 = ic * 64;
    float acc = 0.f;
    #pragma unroll 8
    for (int j = j0; j < j0 + 64; ++j)
        acc = fmaf(W[(size_t)j * H + k], h[j], acc);
    partial_v[ic * H + k] = acc;
}

// ---------------- K1b: v[k] = sum over 16 chunks
__global__ __launch_bounds__(256) void k1b_v_reduce(const float* __restrict__ partial_v,
                                                    float* __restrict__ v) {
    int k = blockIdx.x * 256 + threadIdx.x;
    float acc = 0.f;
    #pragma unroll
    for (int ic = 0; ic < 16; ++ic)
        acc += partial_v[ic * H + k];
    v[k] = acc;
}

// ---------------- K2: energies[s] = E[s,:] . v  (one 64-lane wave per row)
// Each lane: 4x float4 = 16 floats of the 1024-float row. Shuffle-reduce.
// Energies stored straight into d_out (fp32). Also per-block max of its 4 rows.
__global__ __launch_bounds__(256) void k2_energies(const float* __restrict__ E,
                                                   const float* __restrict__ v,
                                                   float* __restrict__ energies,
                                                   float* __restrict__ bmax) {
    int wave = threadIdx.x >> 6;
    int lane = threadIdx.x & 63;
    int row  = blockIdx.x * 4 + wave;

    const float4* Erow = (const float4*)(E + (size_t)row * H);
    const float4* V4   = (const float4*)v;

    float acc = 0.f;
    #pragma unroll
    for (int p = 0; p < 4; ++p) {
        float4 e4 = Erow[p * 64 + lane];
        float4 v4 = V4[p * 64 + lane];   // 4KB, L1-resident
        acc += e4.x * v4.x + e4.y * v4.y + e4.z * v4.z + e4.w * v4.w;
    }
    // 64-lane shuffle reduce (fixed tree -> deterministic)
    #pragma unroll
    for (int off = 32; off; off >>= 1)
        acc += __shfl_down(acc, off, 64);

    __shared__ float lds[4];
    if (lane == 0) { energies[row] = acc; lds[wave] = acc; }
    __syncthreads();
    if (threadIdx.x == 0)
        bmax[blockIdx.x] = fmaxf(fmaxf(lds[0], lds[1]), fmaxf(lds[2], lds[3]));
}

// ---------------- K3: gmax = max(bmax[0..8192)); out[s] = exp(e-gmax); psum per block
// Each block redundantly reduces the 8192 block-maxes (max is exact/associative,
// so every block gets the identical value -> deterministic, no atomics).
__global__ __launch_bounds__(256) void k3_exp(float* __restrict__ out,
                                              const float* __restrict__ bmax,
                                              float* __restrict__ psum) {
    __shared__ float lds[8];
    int tid = threadIdx.x, lane = tid & 63, wave = tid >> 6;

    float m = -INFINITY;
    for (int i = tid; i < 8192; i += 256)
        m = fmaxf(m, bmax[i]);
    #pragma unroll
    for (int off = 32; off; off >>= 1)
        m = fmaxf(m, __shfl_down(m, off, 64));
    if (lane == 0) lds[wave] = m;
    __syncthreads();
    float gmax = fmaxf(fmaxf(lds[0], lds[1]), fmaxf(lds[2], lds[3]));

    int s = blockIdx.x * 256 + tid;
    float p = __expf(out[s] - gmax);
    out[s] = p;

    float a = p;
    #pragma unroll
    for (int off = 32; off; off >>= 1)
        a += __shfl_down(a, off, 64);
    if (lane == 0) lds[4 + wave] = a;
    __syncthreads();
    if (tid == 0)
        psum[blockIdx.x] = (lds[4] + lds[5]) + (lds[6] + lds[7]);
}

// ---------------- K4: sum = reduce(psum[0..128)); out[s] /= sum
// Fixed-order reduction identical in every block -> deterministic & consistent.
__global__ __launch_bounds__(256) void k4_norm(float* __restrict__ out,
                                               const float* __restrict__ psum) {
    __shared__ float lds[4];
    int tid = threadIdx.x, lane = tid & 63, wave = tid >> 6;

    float a = (tid < 128) ? psum[tid] : 0.f;
    #pragma unroll
    for (int off = 32; off; off >>= 1)
        a += __shfl_down(a, off, 64);
    if (lane == 0) lds[wave] = a;
    __syncthreads();
    float inv = 1.f / ((lds[0] + lds[1]) + (lds[2] + lds[3]));

    int s = blockIdx.x * 256 + tid;
    out[s] *= inv;
}

extern "C" void kernel_launch(void* const* d_in, const int* in_sizes, int n_in,
                              void* d_out, int out_size, void* d_ws, size_t ws_size,
                              hipStream_t stream) {
    const float* h = (const float*)d_in[0];   // [1024]
    const float* E = (const float*)d_in[1];   // [32768,1024]
    const float* W = (const float*)d_in[2];   // [1024,1024]
    // d_in[3] = b : unused — softmax is invariant to the constant shift b.h
    float* out = (float*)d_out;               // [32768] fp32
    float* ws  = (float*)d_ws;

    float* partial_v = ws;                    // 16*1024 floats
    float* v         = ws + 16 * 1024;        // 1024
    float* bmax      = ws + 17 * 1024;        // 8192
    float* psum      = ws + 17 * 1024 + 8192; // 128   (total ~101 KB)

    k1_v_partial<<<64,   256, 0, stream>>>(W, h, partial_v);
    k1b_v_reduce<<<4,    256, 0, stream>>>(partial_v, v);
    k2_energies <<<8192, 256, 0, stream>>>(E, v, out, bmax);
    k3_exp      <<<128,  256, 0, stream>>>(out, bmax, psum);
    k4_norm     <<<128,  256, 0, stream>>>(out, psum);
}

// Round 2
// 39.259 us; speedup vs baseline: 1.0466x; 1.0466x over previous
//
#include <hip/hip_runtime.h>
#include <math.h>

// Attn energies + softmax, MI355X.
// energies = E @ (W^T h)  (b*h constant cancels in softmax)
// H=1024, S=32768, all fp32.

#define H 1024
#define S 32768

// ---------------- K1: partial_v[ic][k] = sum_{rows in chunk ic} W[j][k]*h[j]
// grid 128 = 16 chunks (64 rows) x 8 col-tiles (128 cols), block 256.
// Threads split the 64 rows by parity (t>>7), combined via LDS.
__global__ __launch_bounds__(256) void k1_v_partial(const float* __restrict__ W,
                                                    const float* __restrict__ h,
                                                    float* __restrict__ partial_v) {
    __shared__ float lds[128];
    int ic   = blockIdx.x >> 3;          // 16 chunks of 64 rows
    int tile = blockIdx.x & 7;           // 8 col tiles of 128
    int t    = threadIdx.x;
    int c    = tile * 128 + (t & 127);   // column this thread owns
    int par  = t >> 7;                   // row parity 0/1
    int j0   = ic * 64 + par;
    float acc = 0.f;
    #pragma unroll 8
    for (int i = 0; i < 32; ++i) {
        int j = j0 + 2 * i;
        acc = fmaf(W[(size_t)j * H + c], h[j], acc);
    }
    if (par) lds[t - 128] = acc;
    __syncthreads();
    if (!par) partial_v[ic * H + c] = acc + lds[t];
}

// ---------------- K1b: v[k] = sum over 16 chunks
__global__ __launch_bounds__(256) void k1b_v_reduce(const float* __restrict__ partial_v,
                                                    float* __restrict__ v) {
    int k = blockIdx.x * 256 + threadIdx.x;
    float acc = 0.f;
    #pragma unroll
    for (int ic = 0; ic < 16; ++ic)
        acc += partial_v[ic * H + k];
    v[k] = acc;
}

// ---------------- K2: energies[s] = E[s,:] . v
// 8 rows per block (2 per wave). v staged in LDS once, each LDS fragment
// reused for two E rows -> global VMEM slots all go to the E stream.
__global__ __launch_bounds__(256) void k2_energies(const float* __restrict__ E,
                                                   const float* __restrict__ v,
                                                   float* __restrict__ energies,
                                                   float* __restrict__ bmax) {
    __shared__ float vl[H];
    __shared__ float red[8];
    int t = threadIdx.x;

    ((float4*)vl)[t] = ((const float4*)v)[t];   // 256 x 16B = 4KB
    __syncthreads();

    int wave = t >> 6, lane = t & 63;
    size_t row0 = (size_t)blockIdx.x * 8 + wave * 2;
    const float4* e0 = (const float4*)(E + row0 * H);
    const float4* e1 = (const float4*)(E + (row0 + 1) * H);
    const float4* v4 = (const float4*)vl;

    float a0 = 0.f, a1 = 0.f;
    #pragma unroll
    for (int p = 0; p < 4; ++p) {
        float4 vv = v4[p * 64 + lane];          // ds_read_b128
        float4 x0 = e0[p * 64 + lane];
        float4 x1 = e1[p * 64 + lane];
        a0 += x0.x * vv.x + x0.y * vv.y + x0.z * vv.z + x0.w * vv.w;
        a1 += x1.x * vv.x + x1.y * vv.y + x1.z * vv.z + x1.w * vv.w;
    }
    #pragma unroll
    for (int off = 32; off; off >>= 1) {        // fixed tree -> deterministic
        a0 += __shfl_down(a0, off, 64);
        a1 += __shfl_down(a1, off, 64);
    }
    if (lane == 0) {
        energies[row0]     = a0;
        energies[row0 + 1] = a1;
        red[wave * 2]      = a0;
        red[wave * 2 + 1]  = a1;
    }
    __syncthreads();
    if (t == 0) {
        float m = fmaxf(fmaxf(red[0], red[1]), fmaxf(red[2], red[3]));
        m = fmaxf(m, fmaxf(fmaxf(red[4], red[5]), fmaxf(red[6], red[7])));
        bmax[blockIdx.x] = m;
    }
}

// ---------------- K3: gmax = max(bmax[0..4096)); out[s] = exp(e-gmax); psum per block
// Every block redundantly reduces the 4096 block-maxes (exact, associative,
// fixed order -> identical in all blocks, deterministic, no atomics).
__global__ __launch_bounds__(256) void k3_exp(float* __restrict__ out,
                                              const float* __restrict__ bmax,
                                              float* __restrict__ psum) {
    __shared__ float lds[8];
    int tid = threadIdx.x, lane = tid & 63, wave = tid >> 6;

    float m = -INFINITY;
    #pragma unroll 4
    for (int i = tid; i < 4096; i += 256)
        m = fmaxf(m, bmax[i]);
    #pragma unroll
    for (int off = 32; off; off >>= 1)
        m = fmaxf(m, __shfl_down(m, off, 64));
    if (lane == 0) lds[wave] = m;
    __syncthreads();
    float gmax = fmaxf(fmaxf(lds[0], lds[1]), fmaxf(lds[2], lds[3]));

    int s = blockIdx.x * 256 + tid;
    float p = __expf(out[s] - gmax);
    out[s] = p;

    float a = p;
    #pragma unroll
    for (int off = 32; off; off >>= 1)
        a += __shfl_down(a, off, 64);
    if (lane == 0) lds[4 + wave] = a;
    __syncthreads();
    if (tid == 0)
        psum[blockIdx.x] = (lds[4] + lds[5]) + (lds[6] + lds[7]);
}

// ---------------- K4: sum = reduce(psum[0..128)); out[s] /= sum
__global__ __launch_bounds__(256) void k4_norm(float* __restrict__ out,
                                               const float* __restrict__ psum) {
    __shared__ float lds[4];
    int tid = threadIdx.x, lane = tid & 63, wave = tid >> 6;

    float a = (tid < 128) ? psum[tid] : 0.f;
    #pragma unroll
    for (int off = 32; off; off >>= 1)
        a += __shfl_down(a, off, 64);
    if (lane == 0) lds[wave] = a;
    __syncthreads();
    float inv = 1.f / ((lds[0] + lds[1]) + (lds[2] + lds[3]));

    int s = blockIdx.x * 256 + tid;
    out[s] *= inv;
}

extern "C" void kernel_launch(void* const* d_in, const int* in_sizes, int n_in,
                              void* d_out, int out_size, void* d_ws, size_t ws_size,
                              hipStream_t stream) {
    const float* h = (const float*)d_in[0];   // [1024]
    const float* E = (const float*)d_in[1];   // [32768,1024]
    const float* W = (const float*)d_in[2];   // [1024,1024]
    // d_in[3] = b : unused — softmax is invariant to the constant shift b.h
    float* out = (float*)d_out;               // [32768] fp32
    float* ws  = (float*)d_ws;

    float* partial_v = ws;                    // 16*1024 floats
    float* v         = ws + 16 * 1024;        // 1024
    float* bmax      = ws + 17 * 1024;        // 4096
    float* psum      = ws + 17 * 1024 + 4096; // 128   (total ~86 KB)

    k1_v_partial<<<128,  256, 0, stream>>>(W, h, partial_v);
    k1b_v_reduce<<<4,    256, 0, stream>>>(partial_v, v);
    k2_energies <<<4096, 256, 0, stream>>>(E, v, out, bmax);
    k3_exp      <<<128,  256, 0, stream>>>(out, bmax, psum);
    k4_norm     <<<128,  256, 0, stream>>>(out, psum);
}